// Round 6
// baseline (700.158 us; speedup 1.0000x reference)
//
#include <hip/hip_runtime.h>

#define NODES 100000
#define INDIM 256
#define HDIM 128
#define ODIM 40
#define NPX 12500   // nodes per XCD range (100000/8)

typedef short bf16x8 __attribute__((ext_vector_type(8)));   // 8 bf16 (4 VGPR)
typedef float f32x16 __attribute__((ext_vector_type(16)));  // MFMA 32x32 accumulator

// ---------------- CSR build (XCD-range partitioned) ----------------
// Each xcd-group (blockIdx&7) scans ALL edges, processes only dst in its range.
// Makes counts/cursor atomics and esrc stores XCD-L2-local (perf heuristic only;
// correctness holds for any block->XCD mapping).

__global__ __launch_bounds__(256) void k_hist(const int* __restrict__ dst, int E,
                                              int* __restrict__ counts){
    int xcd = blockIdx.x & 7;
    int g   = blockIdx.x >> 3;            // 0..255
    int lo = xcd * NPX, hi = lo + NPX;
    for(int e = g * 256 + threadIdx.x; e < E; e += 65536){
        int d = dst[e];
        if(d >= lo && d < hi) atomicAdd(&counts[d], 1);
    }
}

__global__ __launch_bounds__(256) void k_fill(const int* __restrict__ src, const int* __restrict__ dst,
                                              int E, int* __restrict__ cursor, int* __restrict__ esrc){
    int xcd = blockIdx.x & 7;
    int g   = blockIdx.x >> 3;
    int lo = xcd * NPX, hi = lo + NPX;
    for(int e = g * 256 + threadIdx.x; e < E; e += 65536){
        int d = dst[e];
        if(d >= lo && d < hi){
            int p = atomicAdd(&cursor[d], 1);
            esrc[p] = src[e];
        }
    }
}

// 256 blocks: per-chunk partial sums
__global__ void k_psum(const int* __restrict__ counts, int* __restrict__ partial, int n){
    __shared__ int sm[256];
    int chunk = (n + 255) >> 8;
    int start = blockIdx.x * chunk;
    int end = min(start + chunk, n);
    int s = 0;
    for(int i = start + threadIdx.x; i < end; i += 256) s += counts[i];
    sm[threadIdx.x] = s;
    __syncthreads();
    for(int off = 128; off > 0; off >>= 1){
        if(threadIdx.x < off) sm[threadIdx.x] += sm[threadIdx.x + off];
        __syncthreads();
    }
    if(threadIdx.x == 0) partial[blockIdx.x] = sm[0];
}

__global__ void k_scan256(const int* __restrict__ partial, int* __restrict__ pscan){
    __shared__ int sm[256];
    int t = threadIdx.x;
    sm[t] = partial[t];
    __syncthreads();
    for(int off = 1; off < 256; off <<= 1){
        int v = (t >= off) ? sm[t - off] : 0;
        __syncthreads();
        sm[t] += v;
        __syncthreads();
    }
    pscan[t] = (t == 0) ? 0 : sm[t - 1];
}

__global__ void k_scan_final(const int* __restrict__ counts, const int* __restrict__ pscan,
                             int n, int E, int* __restrict__ row_start, int* __restrict__ cursor,
                             float* __restrict__ dinv){
    __shared__ int sm[512];
    int chunk = (n + 255) >> 8;
    int b = blockIdx.x, t = threadIdx.x;
    int idx = b * chunk + t;
    int c = (t < chunk && idx < n) ? counts[idx] : 0;
    sm[t] = c;
    __syncthreads();
    for(int off = 1; off < 512; off <<= 1){
        int v = (t >= off) ? sm[t - off] : 0;
        __syncthreads();
        sm[t] += v;
        __syncthreads();
    }
    if(t < chunk && idx < n){
        int rs = pscan[b] + sm[t] - c;   // exclusive
        row_start[idx] = rs;
        cursor[idx] = rs;
        dinv[idx] = rsqrtf((float)(c + 1));   // +1 self loop
    }
    if(b == 0 && t == 0) row_start[n] = E;
}

// ---------------- W1 split/transpose into MFMA-fragment order ----------------
// Element (cf, kk, lane, i): col = cf*32 + (lane&31), k = kk*16 + (lane>>5)*8 + i.
// Stored at short index ((cf*16+kk)*64 + lane)*8 + i  -> B loads in k_gemm1 are
// fully coalesced 16B/lane wave loads.
__global__ void k_wsplit(const float* __restrict__ W, unsigned short* __restrict__ whi,
                         unsigned short* __restrict__ wlo){
    int t = blockIdx.x * 256 + threadIdx.x;      // 4096 threads = (cf,kk,lane)
    int lane = t & 63;
    int kk = (t >> 6) & 15;
    int cf = t >> 10;
    int col = cf * 32 + (lane & 31);
    int kbase = kk * 16 + (lane >> 5) * 8;
    #pragma unroll
    for(int i = 0; i < 8; ++i){
        float f = W[(size_t)(kbase + i) * HDIM + col];
        unsigned u = __float_as_uint(f);
        unsigned short hs = (unsigned short)(u >> 16);
        float lf = f - __uint_as_float(u & 0xffff0000u);
        unsigned short ls = (unsigned short)(__float_as_uint(lf) >> 16);
        whi[(size_t)t * 8 + i] = hs;
        wlo[(size_t)t * 8 + i] = ls;
    }
}

// ---------------- GEMM1 (MFMA split-bf16): h' = dinv .* (x @ W1) ----------------
// One wave = 32 rows x 128 cols. A lane-local from global (split in-register),
// B streams from fragment-ordered whi/wlo (L2-resident 128 KB, coalesced).
// C/D: col=lane&31, row=(reg&3)+8*(reg>>2)+4*(lane>>5)  [m74/m101-verified]
__device__ inline void split8(const float4 v0, const float4 v1, bf16x8& hi, bf16x8& lo){
    const float f[8] = {v0.x, v0.y, v0.z, v0.w, v1.x, v1.y, v1.z, v1.w};
    #pragma unroll
    for(int i = 0; i < 8; ++i){
        unsigned u = __float_as_uint(f[i]);
        hi[i] = (short)(u >> 16);
        float lf = f[i] - __uint_as_float(u & 0xffff0000u);
        lo[i] = (short)(__float_as_uint(lf) >> 16);
    }
}

__global__ __launch_bounds__(256, 3) void k_gemm1(const float* __restrict__ x,
        const bf16x8* __restrict__ whi, const bf16x8* __restrict__ wlo,
        const float* __restrict__ dinv, float* __restrict__ h, int n){
    int wid = blockIdx.x * 4 + (threadIdx.x >> 6);
    if(wid >= (n >> 5)) return;              // 3125 waves exactly (100000 = 32*3125)
    int lane = threadIdx.x & 63;
    int r  = lane & 31;
    int hk = lane >> 5;
    int row0 = wid * 32;

    f32x16 acc[4];
    #pragma unroll
    for(int cf = 0; cf < 4; ++cf)
        #pragma unroll
        for(int i = 0; i < 16; ++i) acc[cf][i] = 0.f;

    const float* ap = x + (size_t)(row0 + r) * INDIM + hk * 8;

    for(int kk = 0; kk < 16; ++kk){          // K = 256, BK = 16
        int ko = kk * 16;
        float4 a0 = *(const float4*)(ap + ko);
        float4 a1 = *(const float4*)(ap + ko + 4);
        bf16x8 bh[4], bl[4];
        #pragma unroll
        for(int cf = 0; cf < 4; ++cf){
            bh[cf] = whi[(cf * 16 + kk) * 64 + lane];
            bl[cf] = wlo[(cf * 16 + kk) * 64 + lane];
        }
        bf16x8 ah, al;
        split8(a0, a1, ah, al);
        #pragma unroll
        for(int cf = 0; cf < 4; ++cf){
            acc[cf] = __builtin_amdgcn_mfma_f32_32x32x16_bf16(ah, bh[cf], acc[cf], 0, 0, 0);
            acc[cf] = __builtin_amdgcn_mfma_f32_32x32x16_bf16(ah, bl[cf], acc[cf], 0, 0, 0);
            acc[cf] = __builtin_amdgcn_mfma_f32_32x32x16_bf16(al, bh[cf], acc[cf], 0, 0, 0);
        }
    }

    #pragma unroll
    for(int reg = 0; reg < 16; ++reg){
        int row = row0 + (reg & 3) + 8 * (reg >> 2) + 4 * hk;
        float di = dinv[row];
        float* hp = h + (size_t)row * HDIM + r;
        #pragma unroll
        for(int cf = 0; cf < 4; ++cf)
            hp[cf * 32] = acc[cf][reg] * di;
    }
}

// ---------------- GEMM2: h' = dinv .* (a @ W2), [N,128]@[128,40] ----------------
__global__ __launch_bounds__(256) void k_gemm2(const float* __restrict__ a, const float* __restrict__ W,
                                               const float* __restrict__ dinv,
                                               float* __restrict__ h, int n){
    __shared__ float xs[64][132];
    __shared__ float ws[HDIM][ODIM];
    int tid = threadIdx.x;
    int row0 = blockIdx.x * 64;
    #pragma unroll
    for(int jj = 0; jj < 8; ++jj){
        int f = tid + 256 * jj;       // float4 index, 2048 total
        int r = f >> 5;
        int c4 = (f & 31) << 2;
        float4 v = make_float4(0.f, 0.f, 0.f, 0.f);
        int grow = row0 + r;
        if(grow < n) v = *(const float4*)&a[(size_t)grow * HDIM + c4];
        *(float4*)&xs[r][c4] = v;
    }
    #pragma unroll
    for(int jj = 0; jj < 5; ++jj){
        int f = tid + 256 * jj;       // 1280 float4 exact
        int r = f / 10;
        int c4 = (f % 10) << 2;
        *(float4*)&ws[r][c4] = *(const float4*)&W[(size_t)r * ODIM + c4];
    }
    __syncthreads();
    int q = tid & 3, r = tid >> 2;
    float acc[10];
    #pragma unroll
    for(int j = 0; j < 10; ++j) acc[j] = 0.f;
    #pragma unroll 4
    for(int k = 0; k < HDIM; ++k){
        float xv = xs[r][k];
        #pragma unroll
        for(int j = 0; j < 5; ++j){
            float2 w = *(const float2*)&ws[k][2 * q + 8 * j];
            acc[2*j+0] += xv * w.x;
            acc[2*j+1] += xv * w.y;
        }
    }
    int grow = row0 + r;
    if(grow < n){
        float dv = dinv[grow];
        #pragma unroll
        for(int j = 0; j < 5; ++j){
            float2 o; o.x = acc[2*j] * dv; o.y = acc[2*j+1] * dv;
            *(float2*)&h[(size_t)grow * ODIM + 2 * q + 8 * j] = o;
        }
    }
}

// ---------------- Aggregation (gather over CSR, rows pre-scaled by dinv[src]) ----------------
// Masked 8-deep unroll: 8 gathers always in flight (invalid lanes clamp to e0,
// whose line is L1-hot; accumulate predicated).
__global__ __launch_bounds__(256) void k_agg1(const float* __restrict__ h, const int* __restrict__ row_start,
                                              const int* __restrict__ esrc, const float* __restrict__ dinv,
                                              const float* __restrict__ bias, float* __restrict__ out, int n){
    int wid = (blockIdx.x * 256 + threadIdx.x) >> 6;
    int lane = threadIdx.x & 63;
    if(wid >= n) return;
    int c = lane * 2;
    float2 v = *(const float2*)&h[(size_t)wid * HDIM + c];
    float a0 = v.x, a1 = v.y;                      // self loop: h'[i]
    int e0 = row_start[wid], e1 = row_start[wid + 1];
    for(int base = e0; base < e1; base += 8){
        #pragma unroll
        for(int j = 0; j < 8; ++j){
            int idx = base + j;
            bool val = idx < e1;
            int s = esrc[val ? idx : e0];
            float2 m = *(const float2*)&h[(size_t)s * HDIM + c];
            if(val){ a0 += m.x; a1 += m.y; }
        }
    }
    float di = dinv[wid];
    float2 o;
    o.x = fmaxf(fmaf(a0, di, bias[c]),     0.f);
    o.y = fmaxf(fmaf(a1, di, bias[c + 1]), 0.f);
    *(float2*)&out[(size_t)wid * HDIM + c] = o;
}

__global__ __launch_bounds__(256) void k_agg2(const float* __restrict__ h, const int* __restrict__ row_start,
                                              const int* __restrict__ esrc, const float* __restrict__ dinv,
                                              const float* __restrict__ bias, float* __restrict__ out, int n){
    int wid = (blockIdx.x * 256 + threadIdx.x) >> 6;
    int lane = threadIdx.x & 63;
    if(wid >= n || lane >= ODIM) return;
    float a = h[(size_t)wid * ODIM + lane];        // self loop: h'[i]
    int e0 = row_start[wid], e1 = row_start[wid + 1];
    for(int base = e0; base < e1; base += 8){
        #pragma unroll
        for(int j = 0; j < 8; ++j){
            int idx = base + j;
            bool val = idx < e1;
            int s = esrc[val ? idx : e0];
            float m = h[(size_t)s * ODIM + lane];
            if(val) a += m;
        }
    }
    out[(size_t)wid * ODIM + lane] = fmaf(a, dinv[wid], bias[lane]);
}

extern "C" void kernel_launch(void* const* d_in, const int* in_sizes, int n_in,
                              void* d_out, int out_size, void* d_ws, size_t ws_size,
                              hipStream_t stream){
    const float* x  = (const float*)d_in[0];
    const int*   ei = (const int*)d_in[1];   // [2][E] int32
    const float* W1 = (const float*)d_in[2];
    const float* b1 = (const float*)d_in[3];
    const float* W2 = (const float*)d_in[4];
    const float* b2 = (const float*)d_in[5];
    float* out = (float*)d_out;

    const int n = NODES;
    const int E = in_sizes[1] / 2;
    const int* esrc_in = ei;
    const int* edst_in = ei + E;

    char* w = (char*)d_ws;
    int*   counts    = (int*)(w + (0u << 19));           // 400 KB
    int*   row_start = (int*)(w + (1u << 19));           // 400 KB (+1)
    int*   cursor    = (int*)(w + (2u << 19));           // 400 KB
    int*   partial   = (int*)(w + (3u << 19));           // 1 KB
    int*   pscan     = (int*)(w + (3u << 19) + 4096);    // 1 KB
    float* dinv      = (float*)(w + (4u << 19));         // 400 KB
    int*   esrc      = (int*)(w + (5u << 19));           // 6.4 MB (ends ~9.0 MB)
    unsigned short* whi = (unsigned short*)(w + (10u << 20));  // 64 KB  W1 frag hi
    unsigned short* wlo = (unsigned short*)(w + (11u << 20));  // 64 KB  W1 frag lo
    float* h1        = (float*)(w + (16u << 20));        // 51.2 MB  [N,128] (pre-scaled)
    float* h1r       = (float*)(w + (68u << 20));        // 51.2 MB  [N,128]
    float* h2        = h1;                                // reuse, 16 MB

    hipMemsetAsync(counts, 0, n * sizeof(int), stream);
    k_hist<<<2048, 256, 0, stream>>>(edst_in, E, counts);
    k_psum<<<256, 256, 0, stream>>>(counts, partial, n);
    k_scan256<<<1, 256, 0, stream>>>(partial, pscan);
    k_scan_final<<<256, 512, 0, stream>>>(counts, pscan, n, E, row_start, cursor, dinv);
    k_fill<<<2048, 256, 0, stream>>>(esrc_in, edst_in, E, cursor, esrc);
    k_wsplit<<<16, 256, 0, stream>>>(W1, whi, wlo);

    k_gemm1<<<(NODES / 32 + 3) / 4, 256, 0, stream>>>(x, (const bf16x8*)whi, (const bf16x8*)wlo,
                                                      dinv, h1, n);
    k_agg1<<<(n * 64 + 255) / 256, 256, 0, stream>>>(h1, row_start, esrc, dinv, b1, h1r, n);
    k_gemm2<<<(n + 63) / 64, 256, 0, stream>>>(h1r, W2, dinv, h2, n);
    k_agg2<<<(n * 64 + 255) / 256, 256, 0, stream>>>(h2, row_start, esrc, dinv, b2, out, n);
}

// Round 7
// 561.901 us; speedup vs baseline: 1.2461x; 1.2461x over previous
//
#include <hip/hip_runtime.h>

#define NODES 100000
#define INDIM 256
#define HDIM 128
#define ODIM 40
#define NPX 12500   // nodes per XCD range (100000/8)

typedef short bf16x8 __attribute__((ext_vector_type(8)));   // 8 bf16 (4 VGPR)
typedef float f32x16 __attribute__((ext_vector_type(16)));  // MFMA 32x32 accumulator

// ---------------- CSR build (XCD-range partitioned) ----------------

__global__ __launch_bounds__(256) void k_hist(const int* __restrict__ dst, int E,
                                              int* __restrict__ counts){
    int xcd = blockIdx.x & 7;
    int g   = blockIdx.x >> 3;            // 0..255
    int lo = xcd * NPX, hi = lo + NPX;
    for(int e = g * 256 + threadIdx.x; e < E; e += 65536){
        int d = dst[e];
        if(d >= lo && d < hi) atomicAdd(&counts[d], 1);
    }
}

__global__ __launch_bounds__(256) void k_fill(const int* __restrict__ src, const int* __restrict__ dst,
                                              int E, int* __restrict__ cursor, int* __restrict__ esrc){
    int xcd = blockIdx.x & 7;
    int g   = blockIdx.x >> 3;
    int lo = xcd * NPX, hi = lo + NPX;
    for(int e = g * 256 + threadIdx.x; e < E; e += 65536){
        int d = dst[e];
        if(d >= lo && d < hi){
            int p = atomicAdd(&cursor[d], 1);
            esrc[p] = src[e];
        }
    }
}

__global__ void k_psum(const int* __restrict__ counts, int* __restrict__ partial, int n){
    __shared__ int sm[256];
    int chunk = (n + 255) >> 8;
    int start = blockIdx.x * chunk;
    int end = min(start + chunk, n);
    int s = 0;
    for(int i = start + threadIdx.x; i < end; i += 256) s += counts[i];
    sm[threadIdx.x] = s;
    __syncthreads();
    for(int off = 128; off > 0; off >>= 1){
        if(threadIdx.x < off) sm[threadIdx.x] += sm[threadIdx.x + off];
        __syncthreads();
    }
    if(threadIdx.x == 0) partial[blockIdx.x] = sm[0];
}

__global__ void k_scan256(const int* __restrict__ partial, int* __restrict__ pscan){
    __shared__ int sm[256];
    int t = threadIdx.x;
    sm[t] = partial[t];
    __syncthreads();
    for(int off = 1; off < 256; off <<= 1){
        int v = (t >= off) ? sm[t - off] : 0;
        __syncthreads();
        sm[t] += v;
        __syncthreads();
    }
    pscan[t] = (t == 0) ? 0 : sm[t - 1];
}

__global__ void k_scan_final(const int* __restrict__ counts, const int* __restrict__ pscan,
                             int n, int E, int* __restrict__ row_start, int* __restrict__ cursor,
                             float* __restrict__ dinv){
    __shared__ int sm[512];
    int chunk = (n + 255) >> 8;
    int b = blockIdx.x, t = threadIdx.x;
    int idx = b * chunk + t;
    int c = (t < chunk && idx < n) ? counts[idx] : 0;
    sm[t] = c;
    __syncthreads();
    for(int off = 1; off < 512; off <<= 1){
        int v = (t >= off) ? sm[t - off] : 0;
        __syncthreads();
        sm[t] += v;
        __syncthreads();
    }
    if(t < chunk && idx < n){
        int rs = pscan[b] + sm[t] - c;   // exclusive
        row_start[idx] = rs;
        cursor[idx] = rs;
        dinv[idx] = rsqrtf((float)(c + 1));   // +1 self loop
    }
    if(b == 0 && t == 0) row_start[n] = E;
}

// ---------------- W1 split/transpose into MFMA-fragment order ----------------
__global__ void k_wsplit(const float* __restrict__ W, unsigned short* __restrict__ whi,
                         unsigned short* __restrict__ wlo){
    int t = blockIdx.x * 256 + threadIdx.x;      // 4096 threads = (cf,kk,lane)
    int lane = t & 63;
    int kk = (t >> 6) & 15;
    int cf = t >> 10;
    int col = cf * 32 + (lane & 31);
    int kbase = kk * 16 + (lane >> 5) * 8;
    #pragma unroll
    for(int i = 0; i < 8; ++i){
        float f = W[(size_t)(kbase + i) * HDIM + col];
        unsigned u = __float_as_uint(f);
        unsigned short hs = (unsigned short)(u >> 16);
        float lf = f - __uint_as_float(u & 0xffff0000u);
        unsigned short ls = (unsigned short)(__float_as_uint(lf) >> 16);
        whi[(size_t)t * 8 + i] = hs;
        wlo[(size_t)t * 8 + i] = ls;
    }
}

// ---------------- GEMM1 (MFMA split-bf16): h' = dinv .* (x @ W1) ----------------
__device__ inline void split8(const float4 v0, const float4 v1, bf16x8& hi, bf16x8& lo){
    const float f[8] = {v0.x, v0.y, v0.z, v0.w, v1.x, v1.y, v1.z, v1.w};
    #pragma unroll
    for(int i = 0; i < 8; ++i){
        unsigned u = __float_as_uint(f[i]);
        hi[i] = (short)(u >> 16);
        float lf = f[i] - __uint_as_float(u & 0xffff0000u);
        lo[i] = (short)(__float_as_uint(lf) >> 16);
    }
}

__global__ __launch_bounds__(256, 3) void k_gemm1(const float* __restrict__ x,
        const bf16x8* __restrict__ whi, const bf16x8* __restrict__ wlo,
        const float* __restrict__ dinv, float* __restrict__ h, int n){
    int wid = blockIdx.x * 4 + (threadIdx.x >> 6);
    if(wid >= (n >> 5)) return;              // 3125 waves exactly (100000 = 32*3125)
    int lane = threadIdx.x & 63;
    int r  = lane & 31;
    int hk = lane >> 5;
    int row0 = wid * 32;

    f32x16 acc[4];
    #pragma unroll
    for(int cf = 0; cf < 4; ++cf)
        #pragma unroll
        for(int i = 0; i < 16; ++i) acc[cf][i] = 0.f;

    const float* ap = x + (size_t)(row0 + r) * INDIM + hk * 8;

    for(int kk = 0; kk < 16; ++kk){          // K = 256, BK = 16
        int ko = kk * 16;
        float4 a0 = *(const float4*)(ap + ko);
        float4 a1 = *(const float4*)(ap + ko + 4);
        bf16x8 bh[4], bl[4];
        #pragma unroll
        for(int cf = 0; cf < 4; ++cf){
            bh[cf] = whi[(cf * 16 + kk) * 64 + lane];
            bl[cf] = wlo[(cf * 16 + kk) * 64 + lane];
        }
        bf16x8 ah, al;
        split8(a0, a1, ah, al);
        #pragma unroll
        for(int cf = 0; cf < 4; ++cf){
            acc[cf] = __builtin_amdgcn_mfma_f32_32x32x16_bf16(ah, bh[cf], acc[cf], 0, 0, 0);
            acc[cf] = __builtin_amdgcn_mfma_f32_32x32x16_bf16(ah, bl[cf], acc[cf], 0, 0, 0);
            acc[cf] = __builtin_amdgcn_mfma_f32_32x32x16_bf16(al, bh[cf], acc[cf], 0, 0, 0);
        }
    }

    #pragma unroll
    for(int reg = 0; reg < 16; ++reg){
        int row = row0 + (reg & 3) + 8 * (reg >> 2) + 4 * hk;
        float di = dinv[row];
        float* hp = h + (size_t)row * HDIM + r;
        #pragma unroll
        for(int cf = 0; cf < 4; ++cf)
            hp[cf * 32] = acc[cf][reg] * di;
    }
}

// ---------------- GEMM2: h' = dinv .* (a @ W2), [N,128]@[128,40] ----------------
__global__ __launch_bounds__(256) void k_gemm2(const float* __restrict__ a, const float* __restrict__ W,
                                               const float* __restrict__ dinv,
                                               float* __restrict__ h, int n){
    __shared__ float xs[64][132];
    __shared__ float ws[HDIM][ODIM];
    int tid = threadIdx.x;
    int row0 = blockIdx.x * 64;
    #pragma unroll
    for(int jj = 0; jj < 8; ++jj){
        int f = tid + 256 * jj;       // float4 index, 2048 total
        int r = f >> 5;
        int c4 = (f & 31) << 2;
        float4 v = make_float4(0.f, 0.f, 0.f, 0.f);
        int grow = row0 + r;
        if(grow < n) v = *(const float4*)&a[(size_t)grow * HDIM + c4];
        *(float4*)&xs[r][c4] = v;
    }
    #pragma unroll
    for(int jj = 0; jj < 5; ++jj){
        int f = tid + 256 * jj;       // 1280 float4 exact
        int r = f / 10;
        int c4 = (f % 10) << 2;
        *(float4*)&ws[r][c4] = *(const float4*)&W[(size_t)r * ODIM + c4];
    }
    __syncthreads();
    int q = tid & 3, r = tid >> 2;
    float acc[10];
    #pragma unroll
    for(int j = 0; j < 10; ++j) acc[j] = 0.f;
    #pragma unroll 4
    for(int k = 0; k < HDIM; ++k){
        float xv = xs[r][k];
        #pragma unroll
        for(int j = 0; j < 5; ++j){
            float2 w = *(const float2*)&ws[k][2 * q + 8 * j];
            acc[2*j+0] += xv * w.x;
            acc[2*j+1] += xv * w.y;
        }
    }
    int grow = row0 + r;
    if(grow < n){
        float dv = dinv[grow];
        #pragma unroll
        for(int j = 0; j < 5; ++j){
            float2 o; o.x = acc[2*j] * dv; o.y = acc[2*j+1] * dv;
            *(float2*)&h[(size_t)grow * ODIM + 2 * q + 8 * j] = o;
        }
    }
}

// ---------------- Aggregation (gather over CSR, rows pre-scaled by dinv[src]) ----------------
// agg1: 2 nodes per wave (half-wave each), float4 per lane (32 lanes x 16B = 512B row).
// Clean 8-deep unroll with named register arrays -> 8 independent gathers in
// flight per half, 16 edges in flight per wave.
__global__ __launch_bounds__(256) void k_agg1(const float4* __restrict__ h4, const int* __restrict__ row_start,
                                              const int* __restrict__ esrc, const float* __restrict__ dinv,
                                              const float4* __restrict__ bias4, float4* __restrict__ out4, int n){
    int wav = (blockIdx.x * 256 + threadIdx.x) >> 6;
    int lane = threadIdx.x & 63;
    int half = lane >> 5;
    int node = wav * 2 + half;
    if(node >= n) return;
    int r32 = lane & 31;                     // float4 column 0..31 (128 feats)

    float4 acc = h4[(size_t)node * 32 + r32];    // self loop: h'[i]
    int e = row_start[node], e1 = row_start[node + 1];

    for(; e + 8 <= e1; e += 8){
        int s[8];
        #pragma unroll
        for(int j = 0; j < 8; ++j) s[j] = esrc[e + j];
        float4 m[8];
        #pragma unroll
        for(int j = 0; j < 8; ++j) m[j] = h4[(size_t)s[j] * 32 + r32];
        #pragma unroll
        for(int j = 0; j < 8; ++j){
            acc.x += m[j].x; acc.y += m[j].y; acc.z += m[j].z; acc.w += m[j].w;
        }
    }
    if(e + 4 <= e1){
        int s[4];
        #pragma unroll
        for(int j = 0; j < 4; ++j) s[j] = esrc[e + j];
        float4 m[4];
        #pragma unroll
        for(int j = 0; j < 4; ++j) m[j] = h4[(size_t)s[j] * 32 + r32];
        #pragma unroll
        for(int j = 0; j < 4; ++j){
            acc.x += m[j].x; acc.y += m[j].y; acc.z += m[j].z; acc.w += m[j].w;
        }
        e += 4;
    }
    for(; e < e1; ++e){
        int s = esrc[e];
        float4 m = h4[(size_t)s * 32 + r32];
        acc.x += m.x; acc.y += m.y; acc.z += m.z; acc.w += m.w;
    }

    float di = dinv[node];
    float4 b = bias4[r32];
    float4 o;
    o.x = fmaxf(fmaf(acc.x, di, b.x), 0.f);
    o.y = fmaxf(fmaf(acc.y, di, b.y), 0.f);
    o.z = fmaxf(fmaf(acc.z, di, b.z), 0.f);
    o.w = fmaxf(fmaf(acc.w, di, b.w), 0.f);
    out4[(size_t)node * 32 + r32] = o;
}

// agg2: dim 40, one wave/node (lanes 0..39), clean 8-deep unroll
__global__ __launch_bounds__(256) void k_agg2(const float* __restrict__ h, const int* __restrict__ row_start,
                                              const int* __restrict__ esrc, const float* __restrict__ dinv,
                                              const float* __restrict__ bias, float* __restrict__ out, int n){
    int wid = (blockIdx.x * 256 + threadIdx.x) >> 6;
    int lane = threadIdx.x & 63;
    if(wid >= n || lane >= ODIM) return;
    float a = h[(size_t)wid * ODIM + lane];        // self loop: h'[i]
    int e = row_start[wid], e1 = row_start[wid + 1];
    for(; e + 8 <= e1; e += 8){
        int s[8];
        #pragma unroll
        for(int j = 0; j < 8; ++j) s[j] = esrc[e + j];
        float m[8];
        #pragma unroll
        for(int j = 0; j < 8; ++j) m[j] = h[(size_t)s[j] * ODIM + lane];
        #pragma unroll
        for(int j = 0; j < 8; ++j) a += m[j];
    }
    if(e + 4 <= e1){
        int s[4];
        #pragma unroll
        for(int j = 0; j < 4; ++j) s[j] = esrc[e + j];
        float m[4];
        #pragma unroll
        for(int j = 0; j < 4; ++j) m[j] = h[(size_t)s[j] * ODIM + lane];
        #pragma unroll
        for(int j = 0; j < 4; ++j) a += m[j];
        e += 4;
    }
    for(; e < e1; ++e){
        int s = esrc[e];
        a += h[(size_t)s * ODIM + lane];
    }
    out[(size_t)wid * ODIM + lane] = fmaf(a, dinv[wid], bias[lane]);
}

extern "C" void kernel_launch(void* const* d_in, const int* in_sizes, int n_in,
                              void* d_out, int out_size, void* d_ws, size_t ws_size,
                              hipStream_t stream){
    const float* x  = (const float*)d_in[0];
    const int*   ei = (const int*)d_in[1];   // [2][E] int32
    const float* W1 = (const float*)d_in[2];
    const float* b1 = (const float*)d_in[3];
    const float* W2 = (const float*)d_in[4];
    const float* b2 = (const float*)d_in[5];
    float* out = (float*)d_out;

    const int n = NODES;
    const int E = in_sizes[1] / 2;
    const int* esrc_in = ei;
    const int* edst_in = ei + E;

    char* w = (char*)d_ws;
    int*   counts    = (int*)(w + (0u << 19));           // 400 KB
    int*   row_start = (int*)(w + (1u << 19));           // 400 KB (+1)
    int*   cursor    = (int*)(w + (2u << 19));           // 400 KB
    int*   partial   = (int*)(w + (3u << 19));           // 1 KB
    int*   pscan     = (int*)(w + (3u << 19) + 4096);    // 1 KB
    float* dinv      = (float*)(w + (4u << 19));         // 400 KB
    int*   esrc      = (int*)(w + (5u << 19));           // 6.4 MB (ends ~9.0 MB)
    unsigned short* whi = (unsigned short*)(w + (10u << 20));  // 64 KB  W1 frag hi
    unsigned short* wlo = (unsigned short*)(w + (11u << 20));  // 64 KB  W1 frag lo
    float* h1        = (float*)(w + (16u << 20));        // 51.2 MB  [N,128] (pre-scaled)
    float* h1r       = (float*)(w + (68u << 20));        // 51.2 MB  [N,128]
    float* h2        = h1;                                // reuse, 16 MB

    hipMemsetAsync(counts, 0, n * sizeof(int), stream);
    k_hist<<<2048, 256, 0, stream>>>(edst_in, E, counts);
    k_psum<<<256, 256, 0, stream>>>(counts, partial, n);
    k_scan256<<<1, 256, 0, stream>>>(partial, pscan);
    k_scan_final<<<256, 512, 0, stream>>>(counts, pscan, n, E, row_start, cursor, dinv);
    k_fill<<<2048, 256, 0, stream>>>(esrc_in, edst_in, E, cursor, esrc);
    k_wsplit<<<16, 256, 0, stream>>>(W1, whi, wlo);

    k_gemm1<<<(NODES / 32 + 3) / 4, 256, 0, stream>>>(x, (const bf16x8*)whi, (const bf16x8*)wlo,
                                                      dinv, h1, n);
    // agg1: 2 nodes/wave -> 50000 waves -> 12500 blocks
    k_agg1<<<(n / 2 + 3) / 4, 256, 0, stream>>>((const float4*)h1, row_start, esrc, dinv,
                                                (const float4*)b1, (float4*)h1r, n);
    k_gemm2<<<(n + 63) / 64, 256, 0, stream>>>(h1r, W2, dinv, h2, n);
    k_agg2<<<(n * 64 + 255) / 256, 256, 0, stream>>>(h2, row_start, esrc, dinv, b2, out, n);
}